// Round 4
// baseline (410.740 us; speedup 1.0000x reference)
//
#include <hip/hip_runtime.h>
#include <stdint.h>

typedef int   v4i  __attribute__((ext_vector_type(4)));
typedef int   v16i __attribute__((ext_vector_type(16)));
typedef float v4f  __attribute__((ext_vector_type(4)));

#define TOK_M 8192   // B*S = 4*2048
#define DIM_K 4096   // IN
#define DIM_N 4096   // OUT

#define GL(src, dst)                                                                   \
  __builtin_amdgcn_global_load_lds((const __attribute__((address_space(1))) void*)(src), \
                                   (__attribute__((address_space(3))) void*)(dst), 16, 0, 0)

// ---------------------------------------------------------------------------
// Kernel 1: weight int32 -> int8 pack + per-row sums (fully coalesced)
// ---------------------------------------------------------------------------
__global__ __launch_bounds__(256) void k_pack_w(const int* __restrict__ w,
                                                int8_t* __restrict__ wq,
                                                float* __restrict__ wsumf) {
    __shared__ int sred[4];
    const int row = blockIdx.x;
    const int tid = threadIdx.x;
    const int4* src = (const int4*)(w + (size_t)row * DIM_K);
    unsigned* dst = (unsigned*)(wq + (size_t)row * DIM_K);
    int sum = 0;
#pragma unroll
    for (int c = 0; c < 4; ++c) {
        int4 iv = src[c * 256 + tid];
        sum += iv.x + iv.y + iv.z + iv.w;
        unsigned p = (unsigned)(iv.x & 255) | ((unsigned)(iv.y & 255) << 8) |
                     ((unsigned)(iv.z & 255) << 16) | ((unsigned)(iv.w & 255) << 24);
        dst[c * 256 + tid] = p;
    }
#pragma unroll
    for (int off = 32; off; off >>= 1) sum += __shfl_xor(sum, off);
    if ((tid & 63) == 0) sred[tid >> 6] = sum;
    __syncthreads();
    if (tid == 0) wsumf[row] = (float)(sred[0] + sred[1] + sred[2] + sred[3]);
}

// ---------------------------------------------------------------------------
// Kernel 2: per-token dynamic quant (coalesced chunked layout)
// ---------------------------------------------------------------------------
__global__ __launch_bounds__(256) void k_quant(const float* __restrict__ x,
                                               int8_t* __restrict__ q,
                                               float* __restrict__ sA,
                                               float* __restrict__ sB,
                                               float* __restrict__ sC) {
    __shared__ float redf[8];
    __shared__ int   redi[4];
    __shared__ float bcast[2];
    const int tok = blockIdx.x;
    const int tid = threadIdx.x;
    const v4f* xr = (const v4f*)(x + (size_t)tok * DIM_K);
    v4f v[4];
    float mn = 0.0f, mx = 0.0f;
#pragma unroll
    for (int c = 0; c < 4; ++c) {
        v[c] = xr[c * 256 + tid];
#pragma unroll
        for (int j = 0; j < 4; ++j) {
            mn = fminf(mn, v[c][j]);
            mx = fmaxf(mx, v[c][j]);
        }
    }
#pragma unroll
    for (int off = 32; off; off >>= 1) {
        mn = fminf(mn, __shfl_xor(mn, off));
        mx = fmaxf(mx, __shfl_xor(mx, off));
    }
    const int wid = tid >> 6;
    if ((tid & 63) == 0) { redf[wid] = mn; redf[4 + wid] = mx; }
    __syncthreads();
    if (tid == 0) {
        float m0 = fminf(fminf(redf[0], redf[1]), fminf(redf[2], redf[3]));
        float m1 = fmaxf(fmaxf(redf[4], redf[5]), fmaxf(redf[6], redf[7]));
        float scale = fmaxf((m1 - m0) / 255.0f, 1.1920928955078125e-07f);
        float zpf = -128.0f - rintf(m0 / scale);
        zpf = fminf(fmaxf(zpf, -128.0f), 127.0f);
        bcast[0] = scale; bcast[1] = zpf;
    }
    __syncthreads();
    const float scale = bcast[0];
    const float zpf   = bcast[1];
    const float inv   = 1.0f / scale;
    int qs = 0;
    unsigned* qo = (unsigned*)(q + (size_t)tok * DIM_K);
#pragma unroll
    for (int c = 0; c < 4; ++c) {
        unsigned p = 0;
#pragma unroll
        for (int j = 0; j < 4; ++j) {
            float qf = rintf(v[c][j] * inv) + zpf;
            qf = fminf(fmaxf(qf, -128.0f), 127.0f);
            int qi = (int)qf;
            qs += qi;
            p |= ((unsigned)(qi & 255)) << (8 * j);
        }
        qo[c * 256 + tid] = p;
    }
#pragma unroll
    for (int off = 32; off; off >>= 1) qs += __shfl_xor(qs, off);
    if ((tid & 63) == 0) redi[wid] = qs;
    __syncthreads();
    if (tid == 0) {
        int qtot = redi[0] + redi[1] + redi[2] + redi[3];
        sA[tok] = scale;
        sB[tok] = scale * zpf;
        sC[tok] = scale * ((float)qtot - 4096.0f * zpf);
    }
}

// ---------------------------------------------------------------------------
// Kernel 3: int8 GEMM 256x256, 8 waves, BK=64, triple-buffer, counted vmcnt,
// 32x32x32 MFMA, ONE barrier per K-tile, compiler-scheduled LDS<->MFMA overlap.
// ---------------------------------------------------------------------------
__global__ __launch_bounds__(512, 2) void k_gemm(const int8_t* __restrict__ A,
                                                 const int8_t* __restrict__ B,
                                                 const float* __restrict__ sA,
                                                 const float* __restrict__ sB,
                                                 const float* __restrict__ sC,
                                                 const float* __restrict__ wsumf,
                                                 const float* __restrict__ scales,
                                                 const float* __restrict__ zeros,
                                                 float* __restrict__ out) {
    extern __shared__ int8_t lds[];   // 3 bufs x (A 16KB + B 16KB) = 96 KB
    const int tid = threadIdx.x;
    const int l = tid & 63;
    const int wid = tid >> 6;

    // T1: XCD swizzle, SQUARE per-XCD chunks (tile grid 32 M x 16 N; 8x8 each)
    const int xcd = blockIdx.x & 7;
    const int idx = blockIdx.x >> 3;                  // 0..63
    const int tm = ((xcd >> 1) * 8 + (idx & 7)) * 256;
    const int tn = ((xcd & 1) * 8 + (idx >> 3)) * 256;

    // staging: thread -> (row=tid>>2, chunk=tid&3); inverse T2 swizzle on the
    // GLOBAL source so LDS[row][p] = global[row][p ^ ((row>>1)&3)].
    const int sr  = tid >> 2;
    const int scg = (tid & 3) ^ ((tid >> 3) & 3);
    const int8_t* aS0 = A + (size_t)(tm + sr) * DIM_K + scg * 16;
    const int8_t* aS1 = A + (size_t)(tm + 128 + sr) * DIM_K + scg * 16;
    const int8_t* bS0 = B + (size_t)(tn + sr) * DIM_K + scg * 16;
    const int8_t* bS1 = B + (size_t)(tn + 128 + sr) * DIM_K + scg * 16;
    const int dA0 = tid * 16;
    const int dA1 = 8192 + tid * 16;

    // 32x32x32 read addressing: row r32 = l&31, k-half kh = l>>5 (16B chunk)
    const int r32 = l & 31;
    const int kh  = l >> 5;
    const int f   = (r32 >> 1) & 3;           // T2 swizzle bits
    const int p0  = (0 + kh) ^ f;             // k-step 0 chunk position
    const int p1  = (2 + kh) ^ f;             // k-step 1 chunk position
    const int wm = (wid >> 2) * 128;          // 2 wave-rows
    const int wn = (wid & 3) * 64;            // 4 wave-cols
    const int aBase = (wm + r32) * 64;                // + m*2048
    const int bBase = 16384 + (wn + r32) * 64;        // + n*2048

    v16i acc[4][2] = {};

    // prologue: stage K-tiles 0,1 into bufs 0,1
    GL(aS0, lds + dA0);          GL(aS1, lds + dA1);
    GL(bS0, lds + 16384 + dA0);  GL(bS1, lds + 16384 + dA1);
    GL(aS0 + 64, lds + 32768 + dA0);          GL(aS1 + 64, lds + 32768 + dA1);
    GL(bS0 + 64, lds + 32768 + 16384 + dA0);  GL(bS1 + 64, lds + 32768 + 16384 + dA1);
    asm volatile("s_waitcnt vmcnt(4)" ::: "memory");
    __builtin_amdgcn_s_barrier();

    int cb = 0, sb = 2;
    for (int kt = 0; kt < 64; ++kt) {
        const int koff = kt * 64 + 128;                // K byte offset of tile kt+2
        const int8_t* Sc = lds + cb * 32768;
        int8_t* St = lds + sb * 32768;

        if (kt < 62) {
            GL(aS0 + koff, St + dA0);
            GL(aS1 + koff, St + dA1);
            GL(bS0 + koff, St + 16384 + dA0);
            GL(bS1 + koff, St + 16384 + dA1);
        }

        // 12 ds_read_b128; compiler interleaves with MFMAs via fine lgkmcnt
        v4i a0k0 = *(const v4i*)(Sc + aBase +    0 + p0 * 16);
        v4i a1k0 = *(const v4i*)(Sc + aBase + 2048 + p0 * 16);
        v4i a2k0 = *(const v4i*)(Sc + aBase + 4096 + p0 * 16);
        v4i a3k0 = *(const v4i*)(Sc + aBase + 6144 + p0 * 16);
        v4i b0k0 = *(const v4i*)(Sc + bBase +    0 + p0 * 16);
        v4i b1k0 = *(const v4i*)(Sc + bBase + 2048 + p0 * 16);
        v4i a0k1 = *(const v4i*)(Sc + aBase +    0 + p1 * 16);
        v4i a1k1 = *(const v4i*)(Sc + aBase + 2048 + p1 * 16);
        v4i a2k1 = *(const v4i*)(Sc + aBase + 4096 + p1 * 16);
        v4i a3k1 = *(const v4i*)(Sc + aBase + 6144 + p1 * 16);
        v4i b0k1 = *(const v4i*)(Sc + bBase +    0 + p1 * 16);
        v4i b1k1 = *(const v4i*)(Sc + bBase + 2048 + p1 * 16);

        acc[0][0] = __builtin_amdgcn_mfma_i32_32x32x32_i8(a0k0, b0k0, acc[0][0], 0, 0, 0);
        acc[0][1] = __builtin_amdgcn_mfma_i32_32x32x32_i8(a0k0, b1k0, acc[0][1], 0, 0, 0);
        acc[1][0] = __builtin_amdgcn_mfma_i32_32x32x32_i8(a1k0, b0k0, acc[1][0], 0, 0, 0);
        acc[1][1] = __builtin_amdgcn_mfma_i32_32x32x32_i8(a1k0, b1k0, acc[1][1], 0, 0, 0);
        acc[2][0] = __builtin_amdgcn_mfma_i32_32x32x32_i8(a2k0, b0k0, acc[2][0], 0, 0, 0);
        acc[2][1] = __builtin_amdgcn_mfma_i32_32x32x32_i8(a2k0, b1k0, acc[2][1], 0, 0, 0);
        acc[3][0] = __builtin_amdgcn_mfma_i32_32x32x32_i8(a3k0, b0k0, acc[3][0], 0, 0, 0);
        acc[3][1] = __builtin_amdgcn_mfma_i32_32x32x32_i8(a3k0, b1k0, acc[3][1], 0, 0, 0);
        acc[0][0] = __builtin_amdgcn_mfma_i32_32x32x32_i8(a0k1, b0k1, acc[0][0], 0, 0, 0);
        acc[0][1] = __builtin_amdgcn_mfma_i32_32x32x32_i8(a0k1, b1k1, acc[0][1], 0, 0, 0);
        acc[1][0] = __builtin_amdgcn_mfma_i32_32x32x32_i8(a1k1, b0k1, acc[1][0], 0, 0, 0);
        acc[1][1] = __builtin_amdgcn_mfma_i32_32x32x32_i8(a1k1, b1k1, acc[1][1], 0, 0, 0);
        acc[2][0] = __builtin_amdgcn_mfma_i32_32x32x32_i8(a2k1, b0k1, acc[2][0], 0, 0, 0);
        acc[2][1] = __builtin_amdgcn_mfma_i32_32x32x32_i8(a2k1, b1k1, acc[2][1], 0, 0, 0);
        acc[3][0] = __builtin_amdgcn_mfma_i32_32x32x32_i8(a3k1, b0k1, acc[3][0], 0, 0, 0);
        acc[3][1] = __builtin_amdgcn_mfma_i32_32x32x32_i8(a3k1, b1k1, acc[3][1], 0, 0, 0);

        if (kt < 62) { asm volatile("s_waitcnt vmcnt(4)" ::: "memory"); }
        else         { asm volatile("s_waitcnt vmcnt(0)" ::: "memory"); }
        __builtin_amdgcn_s_barrier();

        cb = (cb == 2) ? 0 : cb + 1;
        sb = (sb == 2) ? 0 : sb + 1;
    }

    // epilogue: 32x32 C/D layout (HW-verified): col = l&31,
    // row = (reg&3) + 8*(reg>>2) + 4*(l>>5)
    const int gc0 = tn + wn + r32;
    float scl[2], zr[2], wsm[2];
#pragma unroll
    for (int n = 0; n < 2; ++n) {
        const int gc = gc0 + n * 32;
        scl[n] = scales[gc]; zr[n] = zeros[gc]; wsm[n] = wsumf[gc];
    }
#pragma unroll
    for (int m = 0; m < 4; ++m) {
#pragma unroll
        for (int reg = 0; reg < 16; ++reg) {
            const int gr = tm + wm + m * 32 + (reg & 3) + 8 * (reg >> 2) + 4 * kh;
            const float ra = sA[gr], rb = sB[gr], rc = sC[gr];
            float* orow = out + (size_t)gr * DIM_N;
#pragma unroll
            for (int n = 0; n < 2; ++n)
                orow[gc0 + n * 32] =
                    scl[n] * (ra * (float)acc[m][n][reg] - rb * wsm[n] - rc * zr[n]);
        }
    }
}

// ---------------------------------------------------------------------------
extern "C" void kernel_launch(void* const* d_in, const int* in_sizes, int n_in,
                              void* d_out, int out_size, void* d_ws, size_t ws_size,
                              hipStream_t stream) {
    const float* x      = (const float*)d_in[0];
    const int*   w      = (const int*)d_in[1];
    const float* scales = (const float*)d_in[2];
    const float* zeros  = (const float*)d_in[3];
    float* out = (float*)d_out;

    uint8_t* ws = (uint8_t*)d_ws;
    int8_t* q  = (int8_t*)ws;                                  // 32 MiB
    int8_t* wq = (int8_t*)(ws + (size_t)TOK_M * DIM_K);        // 16 MiB
    float* fbuf = (float*)(ws + (size_t)TOK_M * DIM_K + (size_t)DIM_N * DIM_K);
    float* sA    = fbuf;
    float* sB    = fbuf + TOK_M;
    float* sC    = fbuf + 2 * TOK_M;
    float* wsumf = fbuf + 3 * TOK_M;

    k_pack_w<<<DIM_N, 256, 0, stream>>>(w, wq, wsumf);
    k_quant<<<TOK_M, 256, 0, stream>>>(x, q, sA, sB, sC);
    k_gemm<<<512, 512, 98304, stream>>>(q, wq, sA, sB, sC, wsumf, scales, zeros, out);
}